// Round 12
// baseline (262.169 us; speedup 1.0000x reference)
//
#include <hip/hip_runtime.h>
#include <hip/hip_bf16.h>
#include <math.h>

#define N_NODES 50000
#define N_EDGES 800000
#define G_GROUPS 64
#define NEG_SLOPE 0.2f
#define BUCKET 64   // max in-degree capacity; Poisson(16) => P(>=64) ~ 1e-18

typedef __attribute__((ext_vector_type(8))) short bf16x8;
typedef __attribute__((ext_vector_type(4))) float f32x4;

static __device__ __forceinline__ float bf16_lo(unsigned int u) {
    return __uint_as_float(u << 16);
}
static __device__ __forceinline__ float bf16_hi(unsigned int u) {
    return __uint_as_float(u & 0xffff0000u);
}
static __device__ __forceinline__ unsigned short f_to_bf16(float f) {
    unsigned int u = __float_as_uint(f);
    unsigned int r = (u + 0x7fffu + ((u >> 16) & 1u)) >> 16;  // RNE
    return (unsigned short)r;
}

#define GB_BLOCKS 782   // (N_NODES+63)/64
#define CV_BLOCKS 3125  // 800000 x-chunks of 8 floats / 256
#define FB_BLOCKS 3125  // 800000 edges / 256

// ---------------- conv_init: x/W -> bf16; zero cnt + ctx --------------------

__global__ __launch_bounds__(256) void conv_init(const float* __restrict__ x,
                                                 unsigned short* __restrict__ xb,
                                                 const float* __restrict__ W0,
                                                 const float* __restrict__ W1,
                                                 const float* __restrict__ W2,
                                                 const float* __restrict__ W3,
                                                 unsigned short* __restrict__ T0,
                                                 unsigned short* __restrict__ T1,
                                                 unsigned short* __restrict__ T2,
                                                 unsigned short* __restrict__ T3,
                                                 int* __restrict__ cnt,
                                                 float* __restrict__ ctx) {
    int tid = blockIdx.x * 256 + threadIdx.x;  // 0..799999
    if (tid < 65536) {
        int m = tid >> 14;
        int idx = tid & 16383;  // k*128+c
        int k = idx >> 7, c = idx & 127;
        const float* W = (m == 0) ? W0 : (m == 1) ? W1 : (m == 2) ? W2 : W3;
        unsigned short* T = (m == 0) ? T0 : (m == 1) ? T1 : (m == 2) ? T2 : T3;
        T[c * 128 + k] = f_to_bf16(W[idx]);
    }
    if (tid < N_NODES) cnt[tid] = 0;
    if (tid < G_GROUPS * 128) ctx[tid] = 0.f;
    const float4* p = (const float4*)(x + (size_t)tid * 8);
    float4 v0 = p[0], v1 = p[1];
    ushort4 o0, o1;
    o0.x = f_to_bf16(v0.x); o0.y = f_to_bf16(v0.y);
    o0.z = f_to_bf16(v0.z); o0.w = f_to_bf16(v0.w);
    o1.x = f_to_bf16(v1.x); o1.y = f_to_bf16(v1.y);
    o1.z = f_to_bf16(v1.z); o1.w = f_to_bf16(v1.w);
    ushort4* q = (ushort4*)(xb + (size_t)tid * 8);
    q[0] = o0; q[1] = o1;
}

// ---------------- GEMM body + fused attn-coef epilogue ----------------

static __device__ __forceinline__ void gemm_body(const unsigned short* __restrict__ Xb,
                                                 const unsigned short* __restrict__ Wt,
                                                 const float* __restrict__ bias,
                                                 unsigned short* __restrict__ Yb,
                                                 int n, int addBias,
                                                 const float* __restrict__ asrcP,
                                                 const float* __restrict__ adstP,
                                                 float* __restrict__ alsP,
                                                 float* __restrict__ aldP, int H,
                                                 int blk, unsigned short* Wl) {
    char* wl = (char*)Wl;
    int t = threadIdx.x;
#pragma unroll
    for (int i = 0; i < 8; i++) {
        int slot = i * 256 + t;
        int byte = slot * 16;
        int r = byte >> 8;
        int off = byte & 255;
        uint4 v = *(const uint4*)((const char*)Wt + byte);
        *(uint4*)(wl + r * 256 + (off ^ ((r & 7) << 4))) = v;
    }
    __syncthreads();

    int wave = t >> 6, lane = t & 63;
    int lr = lane & 15, lk = lane >> 4;
    int arow = blk * 64 + wave * 16 + lr;
    int arowc = min(arow, n - 1);
    const char* xrow = (const char*)(Xb + (size_t)arowc * 128);
    bf16x8 a[4];
#pragma unroll
    for (int ks = 0; ks < 4; ks++)
        a[ks] = *(const bf16x8*)(xrow + ks * 64 + lk * 16);

    f32x4 zero = {0.f, 0.f, 0.f, 0.f};
    f32x4 acc[8];
#pragma unroll
    for (int j = 0; j < 8; j++) acc[j] = zero;

#pragma unroll
    for (int j = 0; j < 8; j++) {
        int c = j * 16 + lr;
        const char* wrow = wl + c * 256;
        int sw = (c & 7) << 4;
#pragma unroll
        for (int ks = 0; ks < 4; ks++) {
            bf16x8 b = *(const bf16x8*)(wrow + ((ks * 64 + lk * 16) ^ sw));
            acc[j] = __builtin_amdgcn_mfma_f32_16x16x32_bf16(a[ks], b, acc[j], 0, 0, 0);
        }
    }

    int orow0 = blk * 64 + wave * 16 + lk * 4;
    if (!alsP) {
#pragma unroll
        for (int j = 0; j < 8; j++) {
            int c = j * 16 + lr;
            float bv = addBias ? bias[c] : 0.f;
#pragma unroll
            for (int r = 0; r < 4; r++) {
                int orow = orow0 + r;
                if (orow < n) Yb[(size_t)orow * 128 + c] = f_to_bf16(acc[j][r] + bv);
            }
        }
        return;
    }

    // fused attn-coef path (bf16 out)
    __syncthreads();  // all waves done reading Wl; safe to reuse as row stage
    unsigned short* Hl = Wl;  // [64][128]
    int lrow0 = wave * 16 + lk * 4;
#pragma unroll
    for (int j = 0; j < 8; j++) {
        int c = j * 16 + lr;
#pragma unroll
        for (int r = 0; r < 4; r++) {
            int orow = orow0 + r;
            unsigned short hv = f_to_bf16(acc[j][r]);
            Hl[(lrow0 + r) * 128 + c] = hv;
            if (orow < n) Yb[(size_t)orow * 128 + c] = hv;
        }
    }
    __syncthreads();

    int row = t >> 2, q = t & 3;  // row 0..63, quarter 0..3
    int node = blk * 64 + row;
    if (node < n) {
        const unsigned int* hp = (const unsigned int*)(Hl + row * 128 + q * 32);
        const float* ap = asrcP + q * 32;
        const float* dp = adstP + q * 32;
        float s = 0.f, dd = 0.f;
#pragma unroll 4
        for (int i = 0; i < 16; i++) {
            unsigned int u = hp[i];
            float v0 = bf16_lo(u), v1 = bf16_hi(u);
            s  = fmaf(v0, ap[2 * i], s);
            s  = fmaf(v1, ap[2 * i + 1], s);
            dd = fmaf(v0, dp[2 * i], dd);
            dd = fmaf(v1, dp[2 * i + 1], dd);
        }
        if (H == 4) {
            alsP[node * 4 + q] = s;
            aldP[node * 4 + q] = dd;
        } else {
            s += __shfl_xor(s, 1); s += __shfl_xor(s, 2);
            dd += __shfl_xor(dd, 1); dd += __shfl_xor(dd, 2);
            if (q == 0) { alsP[node] = s; aldP[node] = dd; }
        }
    }
}

// ---------------- prep2: striped gemm(xskip)/gemm(hfeat+attn1) || fill ------
// grid 4692: bid%3==0 -> gemm g=bid/3 (0..1563); else fill fb=bid-bid/3-1

__global__ __launch_bounds__(256) void prep2(const unsigned short* __restrict__ Xb,
                                             const unsigned short* __restrict__ WtA,
                                             const unsigned short* __restrict__ WtB,
                                             const float* __restrict__ biasA,
                                             unsigned short* __restrict__ xskip,
                                             unsigned short* __restrict__ hfeat,
                                             const float* __restrict__ as1,
                                             const float* __restrict__ ad1,
                                             float* __restrict__ als,
                                             float* __restrict__ ald,
                                             const int* __restrict__ ei,
                                             int* __restrict__ cnt,
                                             int* __restrict__ colb) {
    __shared__ unsigned short Wl[128 * 128];  // 32 KiB
    int bid = blockIdx.x;
    if (bid % 3 == 0) {
        int g = bid / 3;
        if (g >= 2 * GB_BLOCKS) return;
        if (g < GB_BLOCKS) {
            gemm_body(Xb, WtA, biasA, xskip, N_NODES, 1,
                      nullptr, nullptr, nullptr, nullptr, 0, g, Wl);
        } else {
            gemm_body(Xb, WtB, nullptr, hfeat, N_NODES, 0,
                      as1, ad1, als, ald, 4, g - GB_BLOCKS, Wl);
        }
    } else {
        int fb = bid - bid / 3 - 1;
        int e = fb * 256 + threadIdx.x;
        if (fb >= FB_BLOCKS || e >= N_EDGES) return;
        int src = ei[e];
        int dst = ei[N_EDGES + e];
        int pos = atomicAdd(&cnt[dst], 1);
        if (pos < BUCKET) colb[dst * BUCKET + pos] = src;
    }
}

// ---------------- standalone GEMM (layers 2,3) with fused attn ----------

__global__ __launch_bounds__(256) void gemm_mfma(const unsigned short* __restrict__ Xb,
                                                 const unsigned short* __restrict__ Wt,
                                                 unsigned short* __restrict__ Yb,
                                                 const float* __restrict__ asrcP,
                                                 const float* __restrict__ adstP,
                                                 float* __restrict__ alsP,
                                                 float* __restrict__ aldP, int H) {
    __shared__ unsigned short Wl[128 * 128];
    gemm_body(Xb, Wt, nullptr, Yb, N_NODES, 0,
              asrcP, adstP, alsP, aldP, H, blockIdx.x, Wl);
}

// ---------------- aggregate: bucket CSR, inline self-loop, pipelined p ------
// (256-thread blocks; 1024 regressed — R9: 16-wave workgroups pack poorly)
// MODE 0: hcur_bf16 = relu(agg + bias + xskip_bf16)   (layers 1,2)
// MODE 1: out_f32   = agg + bias                      (layer 3)

template <int H, int MODE>
__global__ __launch_bounds__(256) void aggregate(const unsigned short* __restrict__ hfeat,
                                                 const float* __restrict__ als,
                                                 const float* __restrict__ ald,
                                                 const int* __restrict__ cnt,
                                                 const int* __restrict__ colb,
                                                 const float* __restrict__ bias,
                                                 const unsigned short* __restrict__ xskip,
                                                 float* __restrict__ outf,
                                                 unsigned short* __restrict__ outb, int n) {
    int wave = (blockIdx.x * blockDim.x + threadIdx.x) >> 6;
    int lane = threadIdx.x & 63;
    if (wave >= n) return;
    int d = wave;
    const int CH = (H == 4) ? 16 : 64;  // edges per chunk
    int h2 = (H == 4) ? (lane >> 4) : 0;
    int eoff = (H == 4) ? (lane & 15) : lane;
    int sbase = (H == 4) ? (lane & 48) : 0;
    float aldh = ald[d * H + h2];
    int c0 = 2 * lane;
    int cd = min(cnt[d], BUCKET);
    const int* bkt = colb + d * BUCKET;

    // self-loop term (src == dst)
    float vs = als[d * H + h2] + aldh;
    vs = (vs > 0.f) ? vs : NEG_SLOPE * vs;
    float ps = __expf(fminf(vs, 60.f));
    unsigned int us = *(const unsigned int*)&hfeat[(size_t)d * 128 + c0];
    float psum = (eoff == 0) ? ps : 0.f;
    float a0 = ps * bf16_lo(us);
    float a1 = ps * bf16_hi(us);

    // prologue: p for chunk 0
    int sE = 0;
    float p = 0.f;
    if (cd > 0) {
        int idx = eoff;
        sE = bkt[min(idx, cd - 1)];
        float v = als[sE * H + h2] + aldh;
        v = (v > 0.f) ? v : NEG_SLOPE * v;
        p = (idx < cd) ? __expf(fminf(v, 60.f)) : 0.f;
    }

    for (int ce = 0; ce < cd; ce += CH) {
        psum += p;
        // issue next chunk's col load early (hidden under gathers)
        int nce = ce + CH;
        int sE_n = 0;
        if (nce < cd) sE_n = bkt[min(nce + eoff, cd - 1)];
        // accumulate current chunk
        int nv = min(cd - ce, CH);
        if (nv == CH) {
#pragma unroll
            for (int e = 0; e < CH; e++) {
                int s = __shfl(sE, sbase + e);
                float pe = __shfl(p, sbase + e);
                unsigned int u = *(const unsigned int*)&hfeat[(size_t)s * 128 + c0];
                a0 = fmaf(pe, bf16_lo(u), a0);
                a1 = fmaf(pe, bf16_hi(u), a1);
            }
        } else {
            for (int e = 0; e < nv; e++) {
                int s = __shfl(sE, sbase + e);
                float pe = __shfl(p, sbase + e);
                unsigned int u = *(const unsigned int*)&hfeat[(size_t)s * 128 + c0];
                a0 = fmaf(pe, bf16_lo(u), a0);
                a1 = fmaf(pe, bf16_hi(u), a1);
            }
        }
        // compute next chunk's p (als gather scheduled under the FMAs above)
        float p_n = 0.f;
        if (nce < cd) {
            float v = als[sE_n * H + h2] + aldh;
            v = (v > 0.f) ? v : NEG_SLOPE * v;
            p_n = (nce + eoff < cd) ? __expf(fminf(v, 60.f)) : 0.f;
        }
        sE = sE_n;
        p = p_n;
    }

    // psum reduce within head group
#pragma unroll
    for (int o = 1; o < ((H == 4) ? 16 : 64); o <<= 1)
        psum += __shfl_xor(psum, o);

    float inv = 1.f / psum;
    float o0 = a0 * inv + bias[c0];
    float o1 = a1 * inv + bias[c0 + 1];
    if (MODE == 0) {
        unsigned int ux = *(const unsigned int*)&xskip[(size_t)d * 128 + c0];
        o0 = fmaxf(o0 + bf16_lo(ux), 0.f);
        o1 = fmaxf(o1 + bf16_hi(ux), 0.f);
        unsigned int packed = (unsigned int)f_to_bf16(o0) |
                              ((unsigned int)f_to_bf16(o1) << 16);
        *(unsigned int*)&outb[(size_t)d * 128 + c0] = packed;
    } else {
        outf[(size_t)d * 128 + c0] = o0;
        outf[(size_t)d * 128 + c0 + 1] = o1;
    }
}

// ---------------- pooling (parallel partial sums + atomics; batch sorted) ---

__global__ void pool_partial(const float* __restrict__ h, const int* __restrict__ batch,
                             float* __restrict__ ctx) {
    int c = threadIdx.x;  // 0..127
    int base = blockIdx.x * 32;
    int lim = min(base + 32, N_NODES);
    if (base >= N_NODES) return;
    float acc = 0.f;
    int curg = batch[base];
    for (int node = base; node < lim; node++) {
        int g = batch[node];
        if (g != curg) {
            atomicAdd(&ctx[curg * 128 + c], acc);
            curg = g; acc = 0.f;
        }
        acc += h[(size_t)node * 128 + c];
    }
    atomicAdd(&ctx[curg * 128 + c], acc);
}

__global__ void pool_div(const int* __restrict__ batch, float* __restrict__ ctx) {
    int g = blockIdx.x;   // 0..63
    int c = threadIdx.x;  // 0..127
    int lo = 0, hi = N_NODES;
    while (lo < hi) { int mid = (lo + hi) >> 1; if (batch[mid] < g) lo = mid + 1; else hi = mid; }
    int gs = lo;
    hi = N_NODES;
    while (lo < hi) { int mid = (lo + hi) >> 1; if (batch[mid] < g + 1) lo = mid + 1; else hi = mid; }
    int ge = lo;
    ctx[g * 128 + c] /= fmaxf((float)(ge - gs), 1.f);
}

// ---------------- host ----------------

extern "C" void kernel_launch(void* const* d_in, const int* in_sizes, int n_in,
                              void* d_out, int out_size, void* d_ws, size_t ws_size,
                              hipStream_t stream) {
    const float* x   = (const float*)d_in[0];
    const int*   ei  = (const int*)d_in[1];
    const int*   bat = (const int*)d_in[2];
    const float* Wp  = (const float*)d_in[3];
    const float* bp  = (const float*)d_in[4];
    const float* W1  = (const float*)d_in[5];
    const float* as1 = (const float*)d_in[6];
    const float* ad1 = (const float*)d_in[7];
    const float* b1  = (const float*)d_in[8];
    const float* W2  = (const float*)d_in[9];
    const float* as2 = (const float*)d_in[10];
    const float* ad2 = (const float*)d_in[11];
    const float* b2  = (const float*)d_in[12];
    const float* W3  = (const float*)d_in[13];
    const float* as3 = (const float*)d_in[14];
    const float* ad3 = (const float*)d_in[15];
    const float* b3  = (const float*)d_in[16];

    float* out_h   = (float*)d_out;
    float* out_ctx = out_h + (size_t)N_NODES * 128;

    char* w = (char*)d_ws;
    unsigned short* xskip = (unsigned short*)w;  w += (size_t)N_NODES * 128 * 2;
    unsigned short* hfeat = (unsigned short*)w;  w += (size_t)N_NODES * 128 * 2;
    unsigned short* hcur  = (unsigned short*)w;  w += (size_t)N_NODES * 128 * 2;
    unsigned short* xb    = (unsigned short*)w;  w += (size_t)N_NODES * 128 * 2;
    unsigned short* Wtp   = (unsigned short*)w;  w += 16384 * 2;
    unsigned short* Wt1   = (unsigned short*)w;  w += 16384 * 2;
    unsigned short* Wt2   = (unsigned short*)w;  w += 16384 * 2;
    unsigned short* Wt3   = (unsigned short*)w;  w += 16384 * 2;
    float* als   = (float*)w;                    w += (size_t)N_NODES * 4 * 4;
    float* ald   = (float*)w;                    w += (size_t)N_NODES * 4 * 4;
    int* cnt     = (int*)w;                      w += (size_t)N_NODES * 4;
    int* colb    = (int*)w;                      w += (size_t)N_NODES * BUCKET * 4;

    // convert x/W to bf16; zero cnt + ctx (no memsets, no CSR count/scan)
    conv_init<<<CV_BLOCKS, 256, 0, stream>>>(x, xb, Wp, W1, W2, W3,
                                             Wtp, Wt1, Wt2, Wt3, cnt, out_ctx);

    // striped: gemm(xskip,bf16) / gemm(hfeat=x@W1, fused attn1) / fill buckets
    prep2<<<4692, 256, 0, stream>>>(xb, Wtp, Wt1, bp, xskip, hfeat,
                                    as1, ad1, als, ald, ei, cnt, colb);

    const int AGB = (N_NODES * 64 + 255) / 256;  // 12500

    // layer 1 aggregate
    aggregate<4, 0><<<AGB, 256, 0, stream>>>(hfeat, als, ald, cnt, colb, b1, xskip,
                                             nullptr, hcur, N_NODES);

    // layer 2: gemm + fused attn2
    gemm_mfma<<<GB_BLOCKS, 256, 0, stream>>>(hcur, Wt2, hfeat, as2, ad2, als, ald, 4);
    aggregate<4, 0><<<AGB, 256, 0, stream>>>(hfeat, als, ald, cnt, colb, b2, xskip,
                                             nullptr, hcur, N_NODES);

    // layer 3: gemm + fused attn3 (H=1) -> d_out
    gemm_mfma<<<GB_BLOCKS, 256, 0, stream>>>(hcur, Wt3, hfeat, as3, ad3, als, ald, 1);
    aggregate<1, 1><<<AGB, 256, 0, stream>>>(hfeat, als, ald, cnt, colb, b3, nullptr,
                                             out_h, nullptr, N_NODES);

    // global mean pool
    pool_partial<<<(N_NODES + 31) / 32, 128, 0, stream>>>(out_h, bat, out_ctx);
    pool_div<<<G_GROUPS, 128, 0, stream>>>(bat, out_ctx);
}

// Round 13
// 247.826 us; speedup vs baseline: 1.0579x; 1.0579x over previous
//
#include <hip/hip_runtime.h>
#include <hip/hip_bf16.h>
#include <math.h>

#define N_NODES 50000
#define N_EDGES 800000
#define G_GROUPS 64
#define NEG_SLOPE 0.2f
#define BUCKET 64   // max in-degree capacity; Poisson(16) => P(>=64) ~ 1e-18

typedef __attribute__((ext_vector_type(8))) short bf16x8;
typedef __attribute__((ext_vector_type(4))) float f32x4;

static __device__ __forceinline__ float bf16_lo(unsigned int u) {
    return __uint_as_float(u << 16);
}
static __device__ __forceinline__ float bf16_hi(unsigned int u) {
    return __uint_as_float(u & 0xffff0000u);
}
static __device__ __forceinline__ unsigned short f_to_bf16(float f) {
    unsigned int u = __float_as_uint(f);
    unsigned int r = (u + 0x7fffu + ((u >> 16) & 1u)) >> 16;  // RNE
    return (unsigned short)r;
}

#define GB_BLOCKS 782   // (N_NODES+63)/64
#define CV_BLOCKS 3125  // 800000 x-chunks of 8 floats / 256
#define FB_BLOCKS 3125  // 800000 edges / 256

// ---------------- conv_init: x/W -> bf16; zero cnt + ctx --------------------

__global__ __launch_bounds__(256) void conv_init(const float* __restrict__ x,
                                                 unsigned short* __restrict__ xb,
                                                 const float* __restrict__ W0,
                                                 const float* __restrict__ W1,
                                                 const float* __restrict__ W2,
                                                 const float* __restrict__ W3,
                                                 unsigned short* __restrict__ T0,
                                                 unsigned short* __restrict__ T1,
                                                 unsigned short* __restrict__ T2,
                                                 unsigned short* __restrict__ T3,
                                                 int* __restrict__ cnt,
                                                 float* __restrict__ ctx) {
    int tid = blockIdx.x * 256 + threadIdx.x;  // 0..799999
    if (tid < 65536) {
        int m = tid >> 14;
        int idx = tid & 16383;  // k*128+c
        int k = idx >> 7, c = idx & 127;
        const float* W = (m == 0) ? W0 : (m == 1) ? W1 : (m == 2) ? W2 : W3;
        unsigned short* T = (m == 0) ? T0 : (m == 1) ? T1 : (m == 2) ? T2 : T3;
        T[c * 128 + k] = f_to_bf16(W[idx]);
    }
    if (tid < N_NODES) cnt[tid] = 0;
    if (tid < G_GROUPS * 128) ctx[tid] = 0.f;
    const float4* p = (const float4*)(x + (size_t)tid * 8);
    float4 v0 = p[0], v1 = p[1];
    ushort4 o0, o1;
    o0.x = f_to_bf16(v0.x); o0.y = f_to_bf16(v0.y);
    o0.z = f_to_bf16(v0.z); o0.w = f_to_bf16(v0.w);
    o1.x = f_to_bf16(v1.x); o1.y = f_to_bf16(v1.y);
    o1.z = f_to_bf16(v1.z); o1.w = f_to_bf16(v1.w);
    ushort4* q = (ushort4*)(xb + (size_t)tid * 8);
    q[0] = o0; q[1] = o1;
}

// ---------------- GEMM body + fused attn-coef epilogue ----------------

static __device__ __forceinline__ void gemm_body(const unsigned short* __restrict__ Xb,
                                                 const unsigned short* __restrict__ Wt,
                                                 const float* __restrict__ bias,
                                                 unsigned short* __restrict__ Yb,
                                                 int n, int addBias,
                                                 const float* __restrict__ asrcP,
                                                 const float* __restrict__ adstP,
                                                 float* __restrict__ alsP,
                                                 float* __restrict__ aldP, int H,
                                                 int blk, unsigned short* Wl) {
    char* wl = (char*)Wl;
    int t = threadIdx.x;
#pragma unroll
    for (int i = 0; i < 8; i++) {
        int slot = i * 256 + t;
        int byte = slot * 16;
        int r = byte >> 8;
        int off = byte & 255;
        uint4 v = *(const uint4*)((const char*)Wt + byte);
        *(uint4*)(wl + r * 256 + (off ^ ((r & 7) << 4))) = v;
    }
    __syncthreads();

    int wave = t >> 6, lane = t & 63;
    int lr = lane & 15, lk = lane >> 4;
    int arow = blk * 64 + wave * 16 + lr;
    int arowc = min(arow, n - 1);
    const char* xrow = (const char*)(Xb + (size_t)arowc * 128);
    bf16x8 a[4];
#pragma unroll
    for (int ks = 0; ks < 4; ks++)
        a[ks] = *(const bf16x8*)(xrow + ks * 64 + lk * 16);

    f32x4 zero = {0.f, 0.f, 0.f, 0.f};
    f32x4 acc[8];
#pragma unroll
    for (int j = 0; j < 8; j++) acc[j] = zero;

#pragma unroll
    for (int j = 0; j < 8; j++) {
        int c = j * 16 + lr;
        const char* wrow = wl + c * 256;
        int sw = (c & 7) << 4;
#pragma unroll
        for (int ks = 0; ks < 4; ks++) {
            bf16x8 b = *(const bf16x8*)(wrow + ((ks * 64 + lk * 16) ^ sw));
            acc[j] = __builtin_amdgcn_mfma_f32_16x16x32_bf16(a[ks], b, acc[j], 0, 0, 0);
        }
    }

    int orow0 = blk * 64 + wave * 16 + lk * 4;
    if (!alsP) {
#pragma unroll
        for (int j = 0; j < 8; j++) {
            int c = j * 16 + lr;
            float bv = addBias ? bias[c] : 0.f;
#pragma unroll
            for (int r = 0; r < 4; r++) {
                int orow = orow0 + r;
                if (orow < n) Yb[(size_t)orow * 128 + c] = f_to_bf16(acc[j][r] + bv);
            }
        }
        return;
    }

    // fused attn-coef path (bf16 out)
    __syncthreads();  // all waves done reading Wl; safe to reuse as row stage
    unsigned short* Hl = Wl;  // [64][128]
    int lrow0 = wave * 16 + lk * 4;
#pragma unroll
    for (int j = 0; j < 8; j++) {
        int c = j * 16 + lr;
#pragma unroll
        for (int r = 0; r < 4; r++) {
            int orow = orow0 + r;
            unsigned short hv = f_to_bf16(acc[j][r]);
            Hl[(lrow0 + r) * 128 + c] = hv;
            if (orow < n) Yb[(size_t)orow * 128 + c] = hv;
        }
    }
    __syncthreads();

    int row = t >> 2, q = t & 3;  // row 0..63, quarter 0..3
    int node = blk * 64 + row;
    if (node < n) {
        const unsigned int* hp = (const unsigned int*)(Hl + row * 128 + q * 32);
        const float* ap = asrcP + q * 32;
        const float* dp = adstP + q * 32;
        float s = 0.f, dd = 0.f;
#pragma unroll 4
        for (int i = 0; i < 16; i++) {
            unsigned int u = hp[i];
            float v0 = bf16_lo(u), v1 = bf16_hi(u);
            s  = fmaf(v0, ap[2 * i], s);
            s  = fmaf(v1, ap[2 * i + 1], s);
            dd = fmaf(v0, dp[2 * i], dd);
            dd = fmaf(v1, dp[2 * i + 1], dd);
        }
        if (H == 4) {
            alsP[node * 4 + q] = s;
            aldP[node * 4 + q] = dd;
        } else {
            s += __shfl_xor(s, 1); s += __shfl_xor(s, 2);
            dd += __shfl_xor(dd, 1); dd += __shfl_xor(dd, 2);
            if (q == 0) { alsP[node] = s; aldP[node] = dd; }
        }
    }
}

// ---------------- prep2: striped gemm(xskip)/gemm(hfeat+attn1) || fill ------
// grid 4692: bid%3==0 -> gemm g=bid/3 (0..1563); else fill fb=bid-bid/3-1

__global__ __launch_bounds__(256) void prep2(const unsigned short* __restrict__ Xb,
                                             const unsigned short* __restrict__ WtA,
                                             const unsigned short* __restrict__ WtB,
                                             const float* __restrict__ biasA,
                                             unsigned short* __restrict__ xskip,
                                             unsigned short* __restrict__ hfeat,
                                             const float* __restrict__ as1,
                                             const float* __restrict__ ad1,
                                             float* __restrict__ als,
                                             float* __restrict__ ald,
                                             const int* __restrict__ ei,
                                             int* __restrict__ cnt,
                                             int* __restrict__ colb) {
    __shared__ unsigned short Wl[128 * 128];  // 32 KiB
    int bid = blockIdx.x;
    if (bid % 3 == 0) {
        int g = bid / 3;
        if (g >= 2 * GB_BLOCKS) return;
        if (g < GB_BLOCKS) {
            gemm_body(Xb, WtA, biasA, xskip, N_NODES, 1,
                      nullptr, nullptr, nullptr, nullptr, 0, g, Wl);
        } else {
            gemm_body(Xb, WtB, nullptr, hfeat, N_NODES, 0,
                      as1, ad1, als, ald, 4, g - GB_BLOCKS, Wl);
        }
    } else {
        int fb = bid - bid / 3 - 1;
        int e = fb * 256 + threadIdx.x;
        if (fb >= FB_BLOCKS || e >= N_EDGES) return;
        int src = ei[e];
        int dst = ei[N_EDGES + e];
        int pos = atomicAdd(&cnt[dst], 1);
        if (pos < BUCKET) colb[dst * BUCKET + pos] = src;
    }
}

// ---------------- standalone GEMM (layers 2,3) with fused attn ----------

__global__ __launch_bounds__(256) void gemm_mfma(const unsigned short* __restrict__ Xb,
                                                 const unsigned short* __restrict__ Wt,
                                                 unsigned short* __restrict__ Yb,
                                                 const float* __restrict__ asrcP,
                                                 const float* __restrict__ adstP,
                                                 float* __restrict__ alsP,
                                                 float* __restrict__ aldP, int H) {
    __shared__ unsigned short Wl[128 * 128];
    gemm_body(Xb, Wt, nullptr, Yb, N_NODES, 0,
              asrcP, adstP, alsP, aldP, H, blockIdx.x, Wl);
}

// ---------------- aggregate: bucket CSR, inline self-loop -------------------
// (R12 lesson: manual software-pipelining of the p-phase REGRESSED 48->59us —
//  shfl-carried live ranges serialize with gather FMAs; compiler already
//  schedules the simple form well. Keep the simple loop.)
// (256-thread blocks; 1024 regressed — R9: 16-wave workgroups pack poorly)
// MODE 0: hcur_bf16 = relu(agg + bias + xskip_bf16)   (layers 1,2)
// MODE 1: out_f32   = agg + bias                      (layer 3)

template <int H, int MODE>
__global__ __launch_bounds__(256) void aggregate(const unsigned short* __restrict__ hfeat,
                                                 const float* __restrict__ als,
                                                 const float* __restrict__ ald,
                                                 const int* __restrict__ cnt,
                                                 const int* __restrict__ colb,
                                                 const float* __restrict__ bias,
                                                 const unsigned short* __restrict__ xskip,
                                                 float* __restrict__ outf,
                                                 unsigned short* __restrict__ outb, int n) {
    int wave = (blockIdx.x * blockDim.x + threadIdx.x) >> 6;
    int lane = threadIdx.x & 63;
    if (wave >= n) return;
    int d = wave;
    int h2 = (H == 4) ? (lane >> 4) : 0;
    int eoff = lane & 15;
    int sbase = (H == 4) ? (lane & 48) : 0;
    float aldh = ald[d * H + h2];
    int c0 = 2 * lane;
    int cd = min(cnt[d], BUCKET);
    const int* bkt = colb + d * BUCKET;

    // self-loop term (src == dst)
    float vs = als[d * H + h2] + aldh;
    vs = (vs > 0.f) ? vs : NEG_SLOPE * vs;
    float ps = __expf(fminf(vs, 60.f));
    unsigned int us = *(const unsigned int*)&hfeat[(size_t)d * 128 + c0];
    float psum = (eoff == 0) ? ps : 0.f;
    float a0 = ps * bf16_lo(us);
    float a1 = ps * bf16_hi(us);

    for (int ce = 0; ce < cd; ce += 16) {
        int idx = ce + eoff;
        int idxc = min(idx, cd - 1);
        int sE = bkt[idxc];
        float v = als[sE * H + h2] + aldh;
        v = (v > 0.f) ? v : NEG_SLOPE * v;
        float p = (idx < cd) ? __expf(fminf(v, 60.f)) : 0.f;
        psum += p;
        int nv = min(cd - ce, 16);
        if (nv == 16) {
#pragma unroll
            for (int e = 0; e < 16; e++) {
                int s = __shfl(sE, sbase + e);
                float pe = __shfl(p, sbase + e);
                unsigned int u = *(const unsigned int*)&hfeat[(size_t)s * 128 + c0];
                a0 = fmaf(pe, bf16_lo(u), a0);
                a1 = fmaf(pe, bf16_hi(u), a1);
            }
        } else {
            for (int e = 0; e < nv; e++) {
                int s = __shfl(sE, sbase + e);
                float pe = __shfl(p, sbase + e);
                unsigned int u = *(const unsigned int*)&hfeat[(size_t)s * 128 + c0];
                a0 = fmaf(pe, bf16_lo(u), a0);
                a1 = fmaf(pe, bf16_hi(u), a1);
            }
        }
    }

#pragma unroll
    for (int o = 1; o < 16; o <<= 1)
        psum += __shfl_xor(psum, o);

    float inv = 1.f / psum;
    float o0 = a0 * inv + bias[c0];
    float o1 = a1 * inv + bias[c0 + 1];
    if (MODE == 0) {
        unsigned int ux = *(const unsigned int*)&xskip[(size_t)d * 128 + c0];
        o0 = fmaxf(o0 + bf16_lo(ux), 0.f);
        o1 = fmaxf(o1 + bf16_hi(ux), 0.f);
        unsigned int packed = (unsigned int)f_to_bf16(o0) |
                              ((unsigned int)f_to_bf16(o1) << 16);
        *(unsigned int*)&outb[(size_t)d * 128 + c0] = packed;
    } else {
        outf[(size_t)d * 128 + c0] = o0;
        outf[(size_t)d * 128 + c0 + 1] = o1;
    }
}

// ---------------- pooling (parallel partial sums + atomics; batch sorted) ---

__global__ void pool_partial(const float* __restrict__ h, const int* __restrict__ batch,
                             float* __restrict__ ctx) {
    int c = threadIdx.x;  // 0..127
    int base = blockIdx.x * 32;
    int lim = min(base + 32, N_NODES);
    if (base >= N_NODES) return;
    float acc = 0.f;
    int curg = batch[base];
    for (int node = base; node < lim; node++) {
        int g = batch[node];
        if (g != curg) {
            atomicAdd(&ctx[curg * 128 + c], acc);
            curg = g; acc = 0.f;
        }
        acc += h[(size_t)node * 128 + c];
    }
    atomicAdd(&ctx[curg * 128 + c], acc);
}

__global__ void pool_div(const int* __restrict__ batch, float* __restrict__ ctx) {
    int g = blockIdx.x;   // 0..63
    int c = threadIdx.x;  // 0..127
    int lo = 0, hi = N_NODES;
    while (lo < hi) { int mid = (lo + hi) >> 1; if (batch[mid] < g) lo = mid + 1; else hi = mid; }
    int gs = lo;
    hi = N_NODES;
    while (lo < hi) { int mid = (lo + hi) >> 1; if (batch[mid] < g + 1) lo = mid + 1; else hi = mid; }
    int ge = lo;
    ctx[g * 128 + c] /= fmaxf((float)(ge - gs), 1.f);
}

// ---------------- host ----------------

extern "C" void kernel_launch(void* const* d_in, const int* in_sizes, int n_in,
                              void* d_out, int out_size, void* d_ws, size_t ws_size,
                              hipStream_t stream) {
    const float* x   = (const float*)d_in[0];
    const int*   ei  = (const int*)d_in[1];
    const int*   bat = (const int*)d_in[2];
    const float* Wp  = (const float*)d_in[3];
    const float* bp  = (const float*)d_in[4];
    const float* W1  = (const float*)d_in[5];
    const float* as1 = (const float*)d_in[6];
    const float* ad1 = (const float*)d_in[7];
    const float* b1  = (const float*)d_in[8];
    const float* W2  = (const float*)d_in[9];
    const float* as2 = (const float*)d_in[10];
    const float* ad2 = (const float*)d_in[11];
    const float* b2  = (const float*)d_in[12];
    const float* W3  = (const float*)d_in[13];
    const float* as3 = (const float*)d_in[14];
    const float* ad3 = (const float*)d_in[15];
    const float* b3  = (const float*)d_in[16];

    float* out_h   = (float*)d_out;
    float* out_ctx = out_h + (size_t)N_NODES * 128;

    char* w = (char*)d_ws;
    unsigned short* xskip = (unsigned short*)w;  w += (size_t)N_NODES * 128 * 2;
    unsigned short* hfeat = (unsigned short*)w;  w += (size_t)N_NODES * 128 * 2;
    unsigned short* hcur  = (unsigned short*)w;  w += (size_t)N_NODES * 128 * 2;
    unsigned short* xb    = (unsigned short*)w;  w += (size_t)N_NODES * 128 * 2;
    unsigned short* Wtp   = (unsigned short*)w;  w += 16384 * 2;
    unsigned short* Wt1   = (unsigned short*)w;  w += 16384 * 2;
    unsigned short* Wt2   = (unsigned short*)w;  w += 16384 * 2;
    unsigned short* Wt3   = (unsigned short*)w;  w += 16384 * 2;
    float* als   = (float*)w;                    w += (size_t)N_NODES * 4 * 4;
    float* ald   = (float*)w;                    w += (size_t)N_NODES * 4 * 4;
    int* cnt     = (int*)w;                      w += (size_t)N_NODES * 4;
    int* colb    = (int*)w;                      w += (size_t)N_NODES * BUCKET * 4;

    // convert x/W to bf16; zero cnt + ctx (no memsets, no CSR count/scan)
    conv_init<<<CV_BLOCKS, 256, 0, stream>>>(x, xb, Wp, W1, W2, W3,
                                             Wtp, Wt1, Wt2, Wt3, cnt, out_ctx);

    // striped: gemm(xskip,bf16) / gemm(hfeat=x@W1, fused attn1) / fill buckets
    prep2<<<4692, 256, 0, stream>>>(xb, Wtp, Wt1, bp, xskip, hfeat,
                                    as1, ad1, als, ald, ei, cnt, colb);

    const int AGB = (N_NODES * 64 + 255) / 256;  // 12500

    // layer 1 aggregate
    aggregate<4, 0><<<AGB, 256, 0, stream>>>(hfeat, als, ald, cnt, colb, b1, xskip,
                                             nullptr, hcur, N_NODES);

    // layer 2: gemm + fused attn2
    gemm_mfma<<<GB_BLOCKS, 256, 0, stream>>>(hcur, Wt2, hfeat, as2, ad2, als, ald, 4);
    aggregate<4, 0><<<AGB, 256, 0, stream>>>(hfeat, als, ald, cnt, colb, b2, xskip,
                                             nullptr, hcur, N_NODES);

    // layer 3: gemm + fused attn3 (H=1) -> d_out
    gemm_mfma<<<GB_BLOCKS, 256, 0, stream>>>(hcur, Wt3, hfeat, as3, ad3, als, ald, 1);
    aggregate<1, 1><<<AGB, 256, 0, stream>>>(hfeat, als, ald, cnt, colb, b3, nullptr,
                                             out_h, nullptr, N_NODES);

    // global mean pool
    pool_partial<<<(N_NODES + 31) / 32, 128, 0, stream>>>(out_h, bat, out_ctx);
    pool_div<<<G_GROUPS, 128, 0, stream>>>(bat, out_ctx);
}